// Round 4
// baseline (477.364 us; speedup 1.0000x reference)
//
#include <hip/hip_runtime.h>
#include <hip/hip_bf16.h>

#define B_ 2
#define S_ 2048
#define D_ 1024
#define H_ 16
#define DK_ 64
#define BS_ (B_ * S_)   // 4096

typedef unsigned int u32;
typedef unsigned short u16;
typedef __attribute__((ext_vector_type(8))) short bf16x8;
typedef __attribute__((ext_vector_type(4))) float f32x4;

__device__ __forceinline__ float bf2f(u16 v) {
    union { u32 u; float f; } c; c.u = ((u32)v) << 16; return c.f;
}
__device__ __forceinline__ u16 f2bf(float f) {   // RNE (epilogues / one-time prep)
    union { float f; u32 u; } c; c.f = f;
    u32 u = c.u;
    return (u16)((u + 0x7fffu + ((u >> 16) & 1u)) >> 16);
}
// truncating pack of two f32 -> bf16x2 in ONE v_perm (hot paths; 0.4% worst-case rel err)
__device__ __forceinline__ u32 packtr(float lo, float hi) {
    union { float f; u32 u; } a, b; a.f = lo; b.f = hi;
    return __builtin_amdgcn_perm(b.u, a.u, 0x07060302u);
}

// ---------------- weight transpose+convert: WT[n][k] bf16 ----------------
__global__ __launch_bounds__(256) void transpose_w(
    const float* __restrict__ W, u16* __restrict__ WT, int headMode)
{
    __shared__ __attribute__((aligned(16))) u16 T[64][72];
    const int tid = threadIdx.x;
    const int k0 = blockIdx.x * 64;
    const int n0 = blockIdx.y * 64;
    const int kr = tid >> 4;
    const int n4 = (tid & 15) * 4;
    #pragma unroll
    for (int pass = 0; pass < 4; ++pass) {
        int kk = k0 + pass * 16 + kr;
        const float* p = headMode
            ? (W + (size_t)((n0 + n4) >> 6) * (1024 * 64) + kk * 64 + ((n0 + n4) & 63))
            : (W + (size_t)kk * 1024 + n0 + n4);
        float4 a = *(const float4*)p;
        int krel = pass * 16 + kr;
        T[n4 + 0][krel] = f2bf(a.x);
        T[n4 + 1][krel] = f2bf(a.y);
        T[n4 + 2][krel] = f2bf(a.z);
        T[n4 + 3][krel] = f2bf(a.w);
    }
    __syncthreads();
    const int nr = tid >> 2;
    const int kq = (tid & 3) * 16;
    uint4 o0 = *(const uint4*)&T[nr][kq];
    uint4 o1 = *(const uint4*)&T[nr][kq + 8];
    u16* q = WT + (size_t)(n0 + nr) * 1024 + k0 + kq;
    *(uint4*)q = o0;
    *(uint4*)(q + 8) = o1;
}

// ---------------- V transpose: VT[b][h][dk][t] ----------------
__global__ __launch_bounds__(256) void transpose_v(
    const u16* __restrict__ Vb, u16* __restrict__ VT)
{
    __shared__ __attribute__((aligned(16))) u16 T[64][72];
    const int tid = threadIdx.x;
    const int t0 = blockIdx.x * 64;
    const int bh = blockIdx.y;
    const int b = bh >> 4, h = bh & 15;
    const int tr = tid >> 4;
    const int d4 = (tid & 15) * 4;
    #pragma unroll
    for (int pass = 0; pass < 4; ++pass) {
        int tt = t0 + pass * 16 + tr;
        const u16* p = Vb + (size_t)(b * S_ + tt) * 1024 + h * 64 + d4;
        u32 a = *(const u32*)p;
        u32 c = *(const u32*)(p + 2);
        int trel = pass * 16 + tr;
        T[d4 + 0][trel] = (u16)a;
        T[d4 + 1][trel] = (u16)(a >> 16);
        T[d4 + 2][trel] = (u16)c;
        T[d4 + 3][trel] = (u16)(c >> 16);
    }
    __syncthreads();
    const int dr = tid >> 2;
    const int tq = (tid & 3) * 16;
    uint4 o0 = *(const uint4*)&T[dr][tq];
    uint4 o1 = *(const uint4*)&T[dr][tq + 8];
    u16* q = VT + ((size_t)bh * 64 + dr) * 2048 + t0 + tq;
    *(uint4*)q = o0;
    *(uint4*)(q + 8) = o1;
}

// ---------------- colsum of V batch 1: csums[col] = sum_t V1[t][col] ----------------
__global__ __launch_bounds__(256) void colsum_v1(
    const u16* __restrict__ Vp, float* __restrict__ csums)
{
    __shared__ float red[256];
    const int tid = threadIdx.x;
    const int col = blockIdx.x * 64 + (tid & 63);
    const int r0 = 2048 + blockIdx.y * 256 + (tid >> 6) * 64;
    float s = 0.f;
    #pragma unroll 8
    for (int r = 0; r < 64; ++r)
        s += bf2f(Vp[(size_t)(r0 + r) * 1024 + col]);
    red[tid] = s;
    __syncthreads();
    if (tid < 64) {
        float t = red[tid] + red[tid + 64] + red[tid + 128] + red[tid + 192];
        atomicAdd(&csums[blockIdx.x * 64 + tid], t);
    }
}

// ---------------- bf16 MFMA GEMM, B^T weights, reg-double-buffered ----------------
// Y[4096][1024] = X . WT^T + bias. X is f32 (in_f32=1) or bf16.
// negHalf: negate output rows >= 2048 (for K batch-1 sign fold).
__global__ __launch_bounds__(256, 2) void gemm_bt(
    const void* __restrict__ Xv, int in_f32,
    const u16* __restrict__ WT, const float* __restrict__ bias,
    void* __restrict__ Yv, int out_f32, int negHalf)
{
    __shared__ __attribute__((aligned(16))) u16 As[128][40];
    __shared__ __attribute__((aligned(16))) u16 Bs[128][40];
    const int tid = threadIdx.x;
    const int lane = tid & 63;
    const int wave = tid >> 6;
    const int quad = lane >> 4;
    const int l16 = lane & 15;
    const int m0 = blockIdx.x * 128;
    const int n0 = blockIdx.y * 128;
    const int wm = (wave & 1) * 64, wn = (wave >> 1) * 64;

    const int srow = tid >> 1;
    const int scol = (tid & 1) * 16;

    uint4 areg[2], breg[2];
    auto loadA = [&](int k0) {
        if (in_f32) {
            const float* p = (const float*)Xv + (size_t)(m0 + srow) * 1024 + k0 + scol;
            float4 a0 = *(const float4*)p;
            float4 a1 = *(const float4*)(p + 4);
            float4 a2 = *(const float4*)(p + 8);
            float4 a3 = *(const float4*)(p + 12);
            areg[0] = make_uint4(packtr(a0.x, a0.y), packtr(a0.z, a0.w),
                                 packtr(a1.x, a1.y), packtr(a1.z, a1.w));
            areg[1] = make_uint4(packtr(a2.x, a2.y), packtr(a2.z, a2.w),
                                 packtr(a3.x, a3.y), packtr(a3.z, a3.w));
        } else {
            const u16* p = (const u16*)Xv + (size_t)(m0 + srow) * 1024 + k0 + scol;
            areg[0] = *(const uint4*)p;
            areg[1] = *(const uint4*)(p + 8);
        }
    };
    auto loadB = [&](int k0) {
        const u16* p = WT + (size_t)(n0 + srow) * 1024 + k0 + scol;
        breg[0] = *(const uint4*)p;
        breg[1] = *(const uint4*)(p + 8);
    };

    loadA(0); loadB(0);
    f32x4 acc[4][4] = {};

    for (int k0 = 0; k0 < 1024; k0 += 32) {
        __syncthreads();
        *(uint4*)&As[srow][scol]     = areg[0];
        *(uint4*)&As[srow][scol + 8] = areg[1];
        *(uint4*)&Bs[srow][scol]     = breg[0];
        *(uint4*)&Bs[srow][scol + 8] = breg[1];
        if (k0 + 32 < 1024) { loadA(k0 + 32); loadB(k0 + 32); }
        __syncthreads();

        bf16x8 af[4], bfr[4];
        #pragma unroll
        for (int mt = 0; mt < 4; ++mt)
            af[mt] = *(const bf16x8*)&As[wm + mt * 16 + l16][quad * 8];
        #pragma unroll
        for (int nt = 0; nt < 4; ++nt)
            bfr[nt] = *(const bf16x8*)&Bs[wn + nt * 16 + l16][quad * 8];
        #pragma unroll
        for (int mt = 0; mt < 4; ++mt)
            #pragma unroll
            for (int nt = 0; nt < 4; ++nt)
                acc[mt][nt] = __builtin_amdgcn_mfma_f32_16x16x32_bf16(
                    af[mt], bfr[nt], acc[mt][nt], 0, 0, 0);
    }

    #pragma unroll
    for (int nt = 0; nt < 4; ++nt) {
        const int col = n0 + wn + nt * 16 + l16;
        const float bv = bias[col];
        #pragma unroll
        for (int mt = 0; mt < 4; ++mt) {
            #pragma unroll
            for (int r = 0; r < 4; ++r) {
                const int row = m0 + wm + mt * 16 + quad * 4 + r;
                float v = acc[mt][nt][r] + bv;
                if (negHalf && row >= 2048) v = -v;
                if (out_f32) ((float*)Yv)[(size_t)row * 1024 + col] = v;
                else         ((u16*)Yv)[(size_t)row * 1024 + col] = f2bf(v);
            }
        }
    }
}

// ---------------- fused MFMA attention, batch-axis softmax ----------------
// Kp holds K0 and -K1  =>  dacc = Q0.K0^T - Q1.K1^T = delta (one acc set).
// P0 = sigmoid(delta/8); O0 = P0.V0; O1 = csums - P0.V1.
__global__ __launch_bounds__(256, 3) void attn_mfma(
    const u16* __restrict__ Qb, const u16* __restrict__ Kb,
    const u16* __restrict__ VT, const float* __restrict__ csums,
    u16* __restrict__ Cc)
{
    __shared__ __attribute__((aligned(16))) u16 Ks[2][64][72];  // [b][t][dk]
    __shared__ __attribute__((aligned(16))) u16 Vs[2][64][72];  // [b][dk][t]
    __shared__ __attribute__((aligned(16))) u16 Ps[64][72];     // [s][t]
    // 45 KB -> 3 blocks/CU

    const int tid = threadIdx.x;
    const int lane = tid & 63;
    const int wave = tid >> 6;
    const int quad = lane >> 4;
    const int l16 = lane & 15;
    const int s0 = blockIdx.x * 64;
    const int h = blockIdx.y;
    const int sw = wave * 16;

    const int r_ = tid >> 2;
    const int cq = (tid & 3) * 16;

    // Q fragments straight from global (16B contiguous per lane)
    bf16x8 qf[2][2];
    #pragma unroll
    for (int b = 0; b < 2; ++b)
        #pragma unroll
        for (int ks = 0; ks < 2; ++ks)
            qf[b][ks] = *(const bf16x8*)(Qb + (size_t)(b * S_ + s0 + sw + l16) * 1024
                                          + h * 64 + ks * 32 + quad * 8);

    // preload t-tile 0 into registers
    uint4 kreg[2][2], vreg[2][2];
    #pragma unroll
    for (int b = 0; b < 2; ++b) {
        const u16* pk = Kb + (size_t)(b * S_ + r_) * 1024 + h * 64 + cq;
        kreg[b][0] = *(const uint4*)pk;
        kreg[b][1] = *(const uint4*)(pk + 8);
        const u16* pv = VT + ((size_t)(b * H_ + h) * 64 + r_) * 2048 + cq;
        vreg[b][0] = *(const uint4*)pv;
        vreg[b][1] = *(const uint4*)(pv + 8);
    }

    f32x4 O0[4] = {}, T1[4] = {};

    for (int t0 = 0; t0 < S_; t0 += 64) {
        __syncthreads();                       // prev iter's LDS reads done
        *(uint4*)&Ks[0][r_][cq]     = kreg[0][0];
        *(uint4*)&Ks[0][r_][cq + 8] = kreg[0][1];
        *(uint4*)&Ks[1][r_][cq]     = kreg[1][0];
        *(uint4*)&Ks[1][r_][cq + 8] = kreg[1][1];
        *(uint4*)&Vs[0][r_][cq]     = vreg[0][0];
        *(uint4*)&Vs[0][r_][cq + 8] = vreg[0][1];
        *(uint4*)&Vs[1][r_][cq]     = vreg[1][0];
        *(uint4*)&Vs[1][r_][cq + 8] = vreg[1][1];
        if (t0 + 64 < S_) {                    // prefetch next tile during compute
            const int tn = t0 + 64;
            #pragma unroll
            for (int b = 0; b < 2; ++b) {
                const u16* pk = Kb + (size_t)(b * S_ + tn + r_) * 1024 + h * 64 + cq;
                kreg[b][0] = *(const uint4*)pk;
                kreg[b][1] = *(const uint4*)(pk + 8);
                const u16* pv = VT + ((size_t)(b * H_ + h) * 64 + r_) * 2048 + tn + cq;
                vreg[b][0] = *(const uint4*)pv;
                vreg[b][1] = *(const uint4*)(pv + 8);
            }
        }
        __syncthreads();

        // ---- delta^T tiles: A = K rows (m=t), B = Q (n=s) ----
        f32x4 dacc[4] = {};
        #pragma unroll
        for (int mt = 0; mt < 4; ++mt) {
            #pragma unroll
            for (int ks = 0; ks < 2; ++ks) {
                bf16x8 k0f = *(const bf16x8*)&Ks[0][mt * 16 + l16][ks * 32 + quad * 8];
                dacc[mt] = __builtin_amdgcn_mfma_f32_16x16x32_bf16(k0f, qf[0][ks], dacc[mt], 0, 0, 0);
                bf16x8 k1f = *(const bf16x8*)&Ks[1][mt * 16 + l16][ks * 32 + quad * 8];
                dacc[mt] = __builtin_amdgcn_mfma_f32_16x16x32_bf16(k1f, qf[1][ks], dacc[mt], 0, 0, 0);
            }
        }
        // ---- sigmoid + vectorized P store (row s = sw+l16, 4 contig t per mt) ----
        #pragma unroll
        for (int mt = 0; mt < 4; ++mt) {
            float p[4];
            #pragma unroll
            for (int r = 0; r < 4; ++r) {
                float e = __expf(dacc[mt][r] * -0.125f);
                p[r] = __builtin_amdgcn_rcpf(1.0f + e);
            }
            uint2 w;
            w.x = packtr(p[0], p[1]);
            w.y = packtr(p[2], p[3]);
            *(uint2*)&Ps[sw + l16][mt * 16 + quad * 4] = w;
        }
        // ---- PV (wave-private P readback; lgkmcnt only, no barrier) ----
        bf16x8 pf0 = *(const bf16x8*)&Ps[sw + l16][quad * 8];
        bf16x8 pf1 = *(const bf16x8*)&Ps[sw + l16][32 + quad * 8];
        #pragma unroll
        for (int nt = 0; nt < 4; ++nt) {
            bf16x8 v00 = *(const bf16x8*)&Vs[0][nt * 16 + l16][quad * 8];
            bf16x8 v01 = *(const bf16x8*)&Vs[0][nt * 16 + l16][32 + quad * 8];
            O0[nt] = __builtin_amdgcn_mfma_f32_16x16x32_bf16(pf0, v00, O0[nt], 0, 0, 0);
            O0[nt] = __builtin_amdgcn_mfma_f32_16x16x32_bf16(pf1, v01, O0[nt], 0, 0, 0);
            bf16x8 v10 = *(const bf16x8*)&Vs[1][nt * 16 + l16][quad * 8];
            bf16x8 v11 = *(const bf16x8*)&Vs[1][nt * 16 + l16][32 + quad * 8];
            T1[nt] = __builtin_amdgcn_mfma_f32_16x16x32_bf16(pf0, v10, T1[nt], 0, 0, 0);
            T1[nt] = __builtin_amdgcn_mfma_f32_16x16x32_bf16(pf1, v11, T1[nt], 0, 0, 0);
        }
    }

    // ---- epilogue ----
    #pragma unroll
    for (int nt = 0; nt < 4; ++nt) {
        const int dk = nt * 16 + l16;
        const float cs1 = csums[h * 64 + dk];
        #pragma unroll
        for (int r = 0; r < 4; ++r) {
            const int s = s0 + sw + quad * 4 + r;
            Cc[(size_t)(0 * S_ + s) * 1024 + h * 64 + dk] = f2bf(O0[nt][r]);
            Cc[(size_t)(1 * S_ + s) * 1024 + h * 64 + dk] = f2bf(cs1 - T1[nt][r]);
        }
    }
}

extern "C" void kernel_launch(void* const* d_in, const int* in_sizes, int n_in,
                              void* d_out, int out_size, void* d_ws, size_t ws_size,
                              hipStream_t stream) {
    const float* q  = (const float*)d_in[0];
    const float* k  = (const float*)d_in[1];
    const float* v  = (const float*)d_in[2];
    const float* Wq = (const float*)d_in[3];
    const float* bq = (const float*)d_in[4];
    const float* Wk = (const float*)d_in[5];
    const float* bk = (const float*)d_in[6];
    const float* Wv = (const float*)d_in[7];
    const float* bv = (const float*)d_in[8];
    const float* Wo = (const float*)d_in[9];
    const float* bo = (const float*)d_in[10];

    char* ws = (char*)d_ws;
    const size_t MB = 1024 * 1024;
    u16* WqT = (u16*)(ws + 0 * MB);
    u16* WkT = (u16*)(ws + 2 * MB);
    u16* WvT = (u16*)(ws + 4 * MB);
    u16* WoT = (u16*)(ws + 6 * MB);
    u16* Qp  = (u16*)(ws + 8 * MB);
    u16* Kp  = (u16*)(ws + 16 * MB);
    u16* Vp  = (u16*)(ws + 24 * MB);
    u16* VTv = (u16*)(ws + 32 * MB);
    u16* Cc  = (u16*)(ws + 40 * MB);
    float* csums = (float*)d_out;   // scratch; final gemm overwrites all of d_out

    dim3 blk(256);

    transpose_w<<<dim3(16, 16), blk, 0, stream>>>(Wq, WqT, 1);
    transpose_w<<<dim3(16, 16), blk, 0, stream>>>(Wk, WkT, 1);
    transpose_w<<<dim3(16, 16), blk, 0, stream>>>(Wv, WvT, 1);
    transpose_w<<<dim3(16, 16), blk, 0, stream>>>(Wo, WoT, 0);

    gemm_bt<<<dim3(32, 8), blk, 0, stream>>>(q, 1, WqT, bq, (void*)Qp, 0, 0);
    gemm_bt<<<dim3(32, 8), blk, 0, stream>>>(k, 1, WkT, bk, (void*)Kp, 0, 1); // -K1
    gemm_bt<<<dim3(32, 8), blk, 0, stream>>>(v, 1, WvT, bv, (void*)Vp, 0, 0);

    hipMemsetAsync(d_out, 0, 1024 * sizeof(float), stream);
    colsum_v1<<<dim3(16, 8), blk, 0, stream>>>(Vp, csums);
    transpose_v<<<dim3(32, 32), blk, 0, stream>>>(Vp, VTv);
    attn_mfma<<<dim3(32, 16), blk, 0, stream>>>(Qp, Kp, VTv, csums, Cc);
    gemm_bt<<<dim3(32, 8), blk, 0, stream>>>(Cc, 0, WoT, bo, d_out, 1, 0);
}

// Round 5
// 323.933 us; speedup vs baseline: 1.4737x; 1.4737x over previous
//
#include <hip/hip_runtime.h>
#include <hip/hip_bf16.h>

#define B_ 2
#define S_ 2048
#define D_ 1024
#define H_ 16
#define DK_ 64
#define BS_ (B_ * S_)   // 4096

typedef unsigned int u32;
typedef unsigned short u16;
typedef __attribute__((ext_vector_type(8))) short bf16x8;
typedef __attribute__((ext_vector_type(4))) float f32x4;

__device__ __forceinline__ float bf2f(u16 v) {
    union { u32 u; float f; } c; c.u = ((u32)v) << 16; return c.f;
}
__device__ __forceinline__ u16 f2bf(float f) {   // RNE
    union { float f; u32 u; } c; c.f = f;
    u32 u = c.u;
    return (u16)((u + 0x7fffu + ((u >> 16) & 1u)) >> 16);
}
__device__ __forceinline__ u32 pack2(float a, float b) {
    return (u32)f2bf(a) | ((u32)f2bf(b) << 16);
}
// truncating pack of two f32 -> bf16x2 in ONE v_perm (hot path only)
__device__ __forceinline__ u32 packtr(float lo, float hi) {
    union { float f; u32 u; } a, b; a.f = lo; b.f = hi;
    return __builtin_amdgcn_perm(b.u, a.u, 0x07060302u);
}

// ---------------- f32 -> bf16 elementwise convert ----------------
__global__ __launch_bounds__(256) void convert_bf16(
    const float* __restrict__ X, u16* __restrict__ Y, int n)
{
    int i = (blockIdx.x * 256 + threadIdx.x) * 8;
    if (i < n) {
        float4 a = *(const float4*)(X + i);
        float4 b = *(const float4*)(X + i + 4);
        uint4 o;
        o.x = pack2(a.x, a.y); o.y = pack2(a.z, a.w);
        o.z = pack2(b.x, b.y); o.w = pack2(b.z, b.w);
        *(uint4*)(Y + i) = o;
    }
}

// ---------------- weight transpose+convert: WT[n][k] bf16 ----------------
__global__ __launch_bounds__(256) void transpose_w(
    const float* __restrict__ W, u16* __restrict__ WT, int headMode)
{
    __shared__ __attribute__((aligned(16))) u16 T[64][72];
    const int tid = threadIdx.x;
    const int k0 = blockIdx.x * 64;
    const int n0 = blockIdx.y * 64;
    const int kr = tid >> 4;
    const int n4 = (tid & 15) * 4;
    #pragma unroll
    for (int pass = 0; pass < 4; ++pass) {
        int kk = k0 + pass * 16 + kr;
        const float* p = headMode
            ? (W + (size_t)((n0 + n4) >> 6) * (1024 * 64) + kk * 64 + ((n0 + n4) & 63))
            : (W + (size_t)kk * 1024 + n0 + n4);
        float4 a = *(const float4*)p;
        int krel = pass * 16 + kr;
        T[n4 + 0][krel] = f2bf(a.x);
        T[n4 + 1][krel] = f2bf(a.y);
        T[n4 + 2][krel] = f2bf(a.z);
        T[n4 + 3][krel] = f2bf(a.w);
    }
    __syncthreads();
    const int nr = tid >> 2;
    const int kq = (tid & 3) * 16;
    uint4 o0 = *(const uint4*)&T[nr][kq];
    uint4 o1 = *(const uint4*)&T[nr][kq + 8];
    u16* q = WT + (size_t)(n0 + nr) * 1024 + k0 + kq;
    *(uint4*)q = o0;
    *(uint4*)(q + 8) = o1;
}

// ---------------- V transpose: VT[b][h][dk][t] ----------------
__global__ __launch_bounds__(256) void transpose_v(
    const u16* __restrict__ Vb, u16* __restrict__ VT)
{
    __shared__ __attribute__((aligned(16))) u16 T[64][72];
    const int tid = threadIdx.x;
    const int t0 = blockIdx.x * 64;
    const int bh = blockIdx.y;
    const int b = bh >> 4, h = bh & 15;
    const int tr = tid >> 4;
    const int d4 = (tid & 15) * 4;
    #pragma unroll
    for (int pass = 0; pass < 4; ++pass) {
        int tt = t0 + pass * 16 + tr;
        const u16* p = Vb + (size_t)(b * S_ + tt) * 1024 + h * 64 + d4;
        u32 a = *(const u32*)p;
        u32 c = *(const u32*)(p + 2);
        int trel = pass * 16 + tr;
        T[d4 + 0][trel] = (u16)a;
        T[d4 + 1][trel] = (u16)(a >> 16);
        T[d4 + 2][trel] = (u16)c;
        T[d4 + 3][trel] = (u16)(c >> 16);
    }
    __syncthreads();
    const int dr = tid >> 2;
    const int tq = (tid & 3) * 16;
    uint4 o0 = *(const uint4*)&T[dr][tq];
    uint4 o1 = *(const uint4*)&T[dr][tq + 8];
    u16* q = VT + ((size_t)bh * 64 + dr) * 2048 + t0 + tq;
    *(uint4*)q = o0;
    *(uint4*)(q + 8) = o1;
}

// ---------------- colsum of V batch 1 ----------------
__global__ __launch_bounds__(256) void colsum_v1(
    const u16* __restrict__ Vp, float* __restrict__ csums)
{
    __shared__ float red[256];
    const int tid = threadIdx.x;
    const int col = blockIdx.x * 64 + (tid & 63);
    const int r0 = 2048 + blockIdx.y * 256 + (tid >> 6) * 64;
    float s = 0.f;
    #pragma unroll 8
    for (int r = 0; r < 64; ++r)
        s += bf2f(Vp[(size_t)(r0 + r) * 1024 + col]);
    red[tid] = s;
    __syncthreads();
    if (tid < 64) {
        float t = red[tid] + red[tid + 64] + red[tid + 128] + red[tid + 192];
        atomicAdd(&csums[blockIdx.x * 64 + tid], t);
    }
}

// ---------------- bf16 MFMA GEMM, B^T weights (round-3 structure) ----------------
// Y[4096][1024] = X . WT^T + bias. negHalf: negate rows >= 2048.
__global__ __launch_bounds__(256) void gemm_bt(
    const u16* __restrict__ X, const u16* __restrict__ WT,
    const float* __restrict__ bias, void* __restrict__ Yv,
    int out_f32, int negHalf)
{
    __shared__ __attribute__((aligned(16))) u16 As[128][40];
    __shared__ __attribute__((aligned(16))) u16 Bs[128][40];
    const int tid = threadIdx.x;
    const int lane = tid & 63;
    const int wave = tid >> 6;
    const int quad = lane >> 4;
    const int l16 = lane & 15;
    const int m0 = blockIdx.x * 128;
    const int n0 = blockIdx.y * 128;
    const int wm = (wave & 1) * 64, wn = (wave >> 1) * 64;

    const int srow = tid >> 1;
    const int scol = (tid & 1) * 16;

    f32x4 acc[4][4] = {};

    for (int k0 = 0; k0 < 1024; k0 += 32) {
        __syncthreads();
        {
            const u16* p = X + (size_t)(m0 + srow) * 1024 + k0 + scol;
            *(uint4*)&As[srow][scol]     = *(const uint4*)p;
            *(uint4*)&As[srow][scol + 8] = *(const uint4*)(p + 8);
            const u16* q = WT + (size_t)(n0 + srow) * 1024 + k0 + scol;
            *(uint4*)&Bs[srow][scol]     = *(const uint4*)q;
            *(uint4*)&Bs[srow][scol + 8] = *(const uint4*)(q + 8);
        }
        __syncthreads();
        bf16x8 af[4], bfr[4];
        #pragma unroll
        for (int mt = 0; mt < 4; ++mt)
            af[mt] = *(const bf16x8*)&As[wm + mt * 16 + l16][quad * 8];
        #pragma unroll
        for (int nt = 0; nt < 4; ++nt)
            bfr[nt] = *(const bf16x8*)&Bs[wn + nt * 16 + l16][quad * 8];
        #pragma unroll
        for (int mt = 0; mt < 4; ++mt)
            #pragma unroll
            for (int nt = 0; nt < 4; ++nt)
                acc[mt][nt] = __builtin_amdgcn_mfma_f32_16x16x32_bf16(
                    af[mt], bfr[nt], acc[mt][nt], 0, 0, 0);
    }

    #pragma unroll
    for (int nt = 0; nt < 4; ++nt) {
        const int col = n0 + wn + nt * 16 + l16;
        const float bv = bias[col];
        #pragma unroll
        for (int mt = 0; mt < 4; ++mt) {
            #pragma unroll
            for (int r = 0; r < 4; ++r) {
                const int row = m0 + wm + mt * 16 + quad * 4 + r;
                float v = acc[mt][nt][r] + bv;
                if (negHalf && row >= 2048) v = -v;
                if (out_f32) ((float*)Yv)[(size_t)row * 1024 + col] = v;
                else         ((u16*)Yv)[(size_t)row * 1024 + col] = f2bf(v);
            }
        }
    }
}

// ---------------- fused MFMA attention, batch-axis softmax ----------------
// Kp holds K0 and -K1  =>  dacc = Q0.K0^T - Q1.K1^T (one acc set).
// P0 = sigmoid(dacc/8); O0 = P0.V0; O1 = csums - P0.V1.
// Round-3 staging structure (direct load->LDS, no reg prefetch).
__global__ __launch_bounds__(256) void attn_mfma(
    const u16* __restrict__ Qb, const u16* __restrict__ Kb,
    const u16* __restrict__ VT, const float* __restrict__ csums,
    u16* __restrict__ Cc)
{
    __shared__ __attribute__((aligned(16))) u16 Ks[2][64][72];  // [b][t][dk]
    __shared__ __attribute__((aligned(16))) u16 Vs[2][64][72];  // [b][dk][t]
    __shared__ __attribute__((aligned(16))) u16 Ps[64][72];     // [s][t]

    const int tid = threadIdx.x;
    const int lane = tid & 63;
    const int wave = tid >> 6;
    const int quad = lane >> 4;
    const int l16 = lane & 15;
    const int s0 = blockIdx.x * 64;
    const int h = blockIdx.y;
    const int sw = wave * 16;

    const int r_ = tid >> 2;
    const int cq = (tid & 3) * 16;

    // Q fragments straight from global (16B contiguous per lane)
    bf16x8 qf[2][2];
    #pragma unroll
    for (int b = 0; b < 2; ++b)
        #pragma unroll
        for (int ks = 0; ks < 2; ++ks)
            qf[b][ks] = *(const bf16x8*)(Qb + (size_t)(b * S_ + s0 + sw + l16) * 1024
                                          + h * 64 + ks * 32 + quad * 8);

    f32x4 O0[4] = {}, T1[4] = {};

    for (int t0 = 0; t0 < S_; t0 += 64) {
        __syncthreads();                       // prev iter's LDS reads done
        #pragma unroll
        for (int b = 0; b < 2; ++b) {
            const u16* pk = Kb + (size_t)(b * S_ + t0 + r_) * 1024 + h * 64 + cq;
            *(uint4*)&Ks[b][r_][cq]     = *(const uint4*)pk;
            *(uint4*)&Ks[b][r_][cq + 8] = *(const uint4*)(pk + 8);
            const u16* pv = VT + ((size_t)(b * H_ + h) * 64 + r_) * 2048 + t0 + cq;
            *(uint4*)&Vs[b][r_][cq]     = *(const uint4*)pv;
            *(uint4*)&Vs[b][r_][cq + 8] = *(const uint4*)(pv + 8);
        }
        __syncthreads();

        // ---- delta tiles: A = K rows (m=t), B = Q (n=s) ----
        f32x4 dacc[4] = {};
        #pragma unroll
        for (int mt = 0; mt < 4; ++mt) {
            #pragma unroll
            for (int ks = 0; ks < 2; ++ks) {
                bf16x8 k0f = *(const bf16x8*)&Ks[0][mt * 16 + l16][ks * 32 + quad * 8];
                dacc[mt] = __builtin_amdgcn_mfma_f32_16x16x32_bf16(k0f, qf[0][ks], dacc[mt], 0, 0, 0);
                bf16x8 k1f = *(const bf16x8*)&Ks[1][mt * 16 + l16][ks * 32 + quad * 8];
                dacc[mt] = __builtin_amdgcn_mfma_f32_16x16x32_bf16(k1f, qf[1][ks], dacc[mt], 0, 0, 0);
            }
        }
        // ---- sigmoid + vectorized P store: P[s = sw+l16][t = mt*16+quad*4+r] ----
        #pragma unroll
        for (int mt = 0; mt < 4; ++mt) {
            float p[4];
            #pragma unroll
            for (int r = 0; r < 4; ++r) {
                float e = __expf(dacc[mt][r] * -0.125f);
                p[r] = __builtin_amdgcn_rcpf(1.0f + e);
            }
            uint2 w;
            w.x = packtr(p[0], p[1]);
            w.y = packtr(p[2], p[3]);
            *(uint2*)&Ps[sw + l16][mt * 16 + quad * 4] = w;
        }
        // ---- PV (wave-private P readback; lgkmcnt only, no barrier) ----
        bf16x8 pf0 = *(const bf16x8*)&Ps[sw + l16][quad * 8];
        bf16x8 pf1 = *(const bf16x8*)&Ps[sw + l16][32 + quad * 8];
        #pragma unroll
        for (int nt = 0; nt < 4; ++nt) {
            bf16x8 v00 = *(const bf16x8*)&Vs[0][nt * 16 + l16][quad * 8];
            bf16x8 v01 = *(const bf16x8*)&Vs[0][nt * 16 + l16][32 + quad * 8];
            O0[nt] = __builtin_amdgcn_mfma_f32_16x16x32_bf16(pf0, v00, O0[nt], 0, 0, 0);
            O0[nt] = __builtin_amdgcn_mfma_f32_16x16x32_bf16(pf1, v01, O0[nt], 0, 0, 0);
            bf16x8 v10 = *(const bf16x8*)&Vs[1][nt * 16 + l16][quad * 8];
            bf16x8 v11 = *(const bf16x8*)&Vs[1][nt * 16 + l16][32 + quad * 8];
            T1[nt] = __builtin_amdgcn_mfma_f32_16x16x32_bf16(pf0, v10, T1[nt], 0, 0, 0);
            T1[nt] = __builtin_amdgcn_mfma_f32_16x16x32_bf16(pf1, v11, T1[nt], 0, 0, 0);
        }
    }

    // ---- epilogue ----
    #pragma unroll
    for (int nt = 0; nt < 4; ++nt) {
        const int dk = nt * 16 + l16;
        const float cs1 = csums[h * 64 + dk];
        #pragma unroll
        for (int r = 0; r < 4; ++r) {
            const int s = s0 + sw + quad * 4 + r;
            Cc[(size_t)(0 * S_ + s) * 1024 + h * 64 + dk] = f2bf(O0[nt][r]);
            Cc[(size_t)(1 * S_ + s) * 1024 + h * 64 + dk] = f2bf(cs1 - T1[nt][r]);
        }
    }
}

extern "C" void kernel_launch(void* const* d_in, const int* in_sizes, int n_in,
                              void* d_out, int out_size, void* d_ws, size_t ws_size,
                              hipStream_t stream) {
    const float* q  = (const float*)d_in[0];
    const float* k  = (const float*)d_in[1];
    const float* v  = (const float*)d_in[2];
    const float* Wq = (const float*)d_in[3];
    const float* bq = (const float*)d_in[4];
    const float* Wk = (const float*)d_in[5];
    const float* bk = (const float*)d_in[6];
    const float* Wv = (const float*)d_in[7];
    const float* bv = (const float*)d_in[8];
    const float* Wo = (const float*)d_in[9];
    const float* bo = (const float*)d_in[10];

    char* ws = (char*)d_ws;
    const size_t MB = 1024 * 1024;
    u16* Xb  = (u16*)(ws);             // 8 MB, reused for q/k/v inputs then Cc
    u16* WqT = (u16*)(ws + 8  * MB);
    u16* WkT = (u16*)(ws + 10 * MB);
    u16* WvT = (u16*)(ws + 12 * MB);
    u16* WoT = (u16*)(ws + 14 * MB);
    u16* Qp  = (u16*)(ws + 16 * MB);
    u16* Kp  = (u16*)(ws + 24 * MB);
    u16* Vp  = (u16*)(ws + 32 * MB);
    u16* VTv = (u16*)(ws + 40 * MB);
    u16* Cc  = Xb;                     // reuse (X dead after V projection)
    float* csums = (float*)d_out;      // scratch; final gemm overwrites d_out

    dim3 blk(256);
    const int NEL = BS_ * D_;

    transpose_w<<<dim3(16, 16), blk, 0, stream>>>(Wq, WqT, 1);
    transpose_w<<<dim3(16, 16), blk, 0, stream>>>(Wk, WkT, 1);
    transpose_w<<<dim3(16, 16), blk, 0, stream>>>(Wv, WvT, 1);
    transpose_w<<<dim3(16, 16), blk, 0, stream>>>(Wo, WoT, 0);

    convert_bf16<<<dim3(NEL / (256 * 8)), blk, 0, stream>>>(q, Xb, NEL);
    gemm_bt<<<dim3(32, 8), blk, 0, stream>>>(Xb, WqT, bq, (void*)Qp, 0, 0);
    convert_bf16<<<dim3(NEL / (256 * 8)), blk, 0, stream>>>(k, Xb, NEL);
    gemm_bt<<<dim3(32, 8), blk, 0, stream>>>(Xb, WkT, bk, (void*)Kp, 0, 1); // -K1
    convert_bf16<<<dim3(NEL / (256 * 8)), blk, 0, stream>>>(v, Xb, NEL);
    gemm_bt<<<dim3(32, 8), blk, 0, stream>>>(Xb, WvT, bv, (void*)Vp, 0, 0);

    hipMemsetAsync(d_out, 0, 1024 * sizeof(float), stream);
    colsum_v1<<<dim3(16, 8), blk, 0, stream>>>(Vp, csums);
    transpose_v<<<dim3(32, 32), blk, 0, stream>>>(Vp, VTv);
    attn_mfma<<<dim3(32, 16), blk, 0, stream>>>(Qp, Kp, VTv, csums, Cc);
    gemm_bt<<<dim3(32, 8), blk, 0, stream>>>(Cc, WoT, bo, d_out, 1, 0);
}

// Round 6
// 276.464 us; speedup vs baseline: 1.7267x; 1.1717x over previous
//
#include <hip/hip_runtime.h>
#include <hip/hip_bf16.h>

#define B_ 2
#define S_ 2048
#define D_ 1024
#define H_ 16
#define DK_ 64
#define BS_ (B_ * S_)   // 4096

typedef unsigned int u32;
typedef unsigned short u16;
typedef __attribute__((ext_vector_type(8))) short bf16x8;
typedef __attribute__((ext_vector_type(4))) float f32x4;

__device__ __forceinline__ float bf2f(u16 v) {
    union { u32 u; float f; } c; c.u = ((u32)v) << 16; return c.f;
}
__device__ __forceinline__ u16 f2bf(float f) {   // RNE
    union { float f; u32 u; } c; c.f = f;
    u32 u = c.u;
    return (u16)((u + 0x7fffu + ((u >> 16) & 1u)) >> 16);
}
// truncating pack of two f32 -> bf16x2 in ONE v_perm (hot paths)
__device__ __forceinline__ u32 packtr(float lo, float hi) {
    union { float f; u32 u; } a, b; a.f = lo; b.f = hi;
    return __builtin_amdgcn_perm(b.u, a.u, 0x07060302u);
}
// LDS swizzles: rotate 16B blocks by row so frag accesses spread across banks
__device__ __forceinline__ int sw64(int r, int c8) { return (((c8) + (r)) & 7) * 8; }
__device__ __forceinline__ int sw32(int r, int c8) { return (((c8) + (r)) & 3) * 8; }

// ---------------- weight transpose+convert: WT[n][k] bf16 (z picks matrix) ----
struct WArgs { const float* W[4]; u16* WT[4]; };
__global__ __launch_bounds__(256) void prep_w(WArgs wa)
{
    __shared__ __attribute__((aligned(16))) u16 T[64][72];
    const int z = blockIdx.z;
    const float* W = wa.W[z];
    u16* WT = wa.WT[z];
    const int headMode = (z < 3) ? 1 : 0;
    const int tid = threadIdx.x;
    const int k0 = blockIdx.x * 64;
    const int n0 = blockIdx.y * 64;
    const int kr = tid >> 4;
    const int n4 = (tid & 15) * 4;
    #pragma unroll
    for (int pass = 0; pass < 4; ++pass) {
        int kk = k0 + pass * 16 + kr;
        const float* p = headMode
            ? (W + (size_t)((n0 + n4) >> 6) * (1024 * 64) + kk * 64 + ((n0 + n4) & 63))
            : (W + (size_t)kk * 1024 + n0 + n4);
        float4 a = *(const float4*)p;
        int krel = pass * 16 + kr;
        T[n4 + 0][krel] = f2bf(a.x);
        T[n4 + 1][krel] = f2bf(a.y);
        T[n4 + 2][krel] = f2bf(a.z);
        T[n4 + 3][krel] = f2bf(a.w);
    }
    __syncthreads();
    const int nr = tid >> 2;
    const int kq = (tid & 3) * 16;
    uint4 o0 = *(const uint4*)&T[nr][kq];
    uint4 o1 = *(const uint4*)&T[nr][kq + 8];
    u16* q = WT + (size_t)(n0 + nr) * 1024 + k0 + kq;
    *(uint4*)q = o0;
    *(uint4*)(q + 8) = o1;
}

// ---------------- V transpose + fused colsum(V1): VT[b][h][dk][t] -------------
__global__ __launch_bounds__(256) void vprep(
    const u16* __restrict__ Vb, u16* __restrict__ VT, float* __restrict__ csums)
{
    __shared__ __attribute__((aligned(16))) u16 T[64][72];
    __shared__ float red[256];
    const int tid = threadIdx.x;
    const int t0 = blockIdx.x * 64;
    const int bh = blockIdx.y;
    const int b = bh >> 4, h = bh & 15;
    const int tr = tid >> 4;
    const int d4 = (tid & 15) * 4;
    #pragma unroll
    for (int pass = 0; pass < 4; ++pass) {
        int tt = t0 + pass * 16 + tr;
        const u16* p = Vb + (size_t)(b * S_ + tt) * 1024 + h * 64 + d4;
        u32 a = *(const u32*)p;
        u32 c = *(const u32*)(p + 2);
        int trel = pass * 16 + tr;
        T[d4 + 0][trel] = (u16)a;
        T[d4 + 1][trel] = (u16)(a >> 16);
        T[d4 + 2][trel] = (u16)c;
        T[d4 + 3][trel] = (u16)(c >> 16);
    }
    __syncthreads();
    const int dr = tid >> 2;
    const int tq = (tid & 3) * 16;
    uint4 o0 = *(const uint4*)&T[dr][tq];
    uint4 o1 = *(const uint4*)&T[dr][tq + 8];
    u16* q = VT + ((size_t)bh * 64 + dr) * 2048 + t0 + tq;
    *(uint4*)q = o0;
    *(uint4*)(q + 8) = o1;

    if (b == 1) {   // fused colsum of V batch-1 (T only read after this point)
        const int dk = tid & 63, part = tid >> 6;
        float s = 0.f;
        #pragma unroll
        for (int t = 0; t < 16; ++t) s += bf2f(T[dk][part * 16 + t]);
        red[tid] = s;
        __syncthreads();
        if (tid < 64)
            atomicAdd(&csums[h * 64 + tid],
                      red[tid] + red[tid + 64] + red[tid + 128] + red[tid + 192]);
    }
}

// ---------------- fused projections: Y = X(f32) . WT^T + bias, bf16 out -------
// 128x64 tile, 4 waves 64x32 each, BK=32; z picks (X,W,bias,Y); z==1 negates
// rows >= 2048 (K batch-1 sign fold).
struct ProjArgs {
    const float* X[3];
    const u16* W[3];
    const float* bias[3];
    u16* Y[3];
};
__global__ __launch_bounds__(256) void proj3(ProjArgs pa)
{
    __shared__ __attribute__((aligned(16))) u16 As[128][32];
    __shared__ __attribute__((aligned(16))) u16 Bs[64][32];
    const int z = blockIdx.z;
    const float* X = pa.X[z];
    const u16* WT = pa.W[z];
    const float* bias = pa.bias[z];
    u16* Y = pa.Y[z];
    const int neg = (z == 1);

    const int tid = threadIdx.x;
    const int lane = tid & 63;
    const int wave = tid >> 6;
    const int quad = lane >> 4;
    const int l16 = lane & 15;
    const int m0 = blockIdx.x * 128;
    const int n0 = blockIdx.y * 64;
    const int wm = (wave & 1) * 64, wn = (wave >> 1) * 32;

    const int srow = tid >> 1, half = tid & 1;
    const int brow = tid >> 2, bc8 = tid & 3;

    f32x4 acc[4][2] = {};

    for (int k0 = 0; k0 < 1024; k0 += 32) {
        __syncthreads();
        {   // A: f32 -> bf16 convert fused into staging (16 u16 per thread)
            const float* p = X + (size_t)(m0 + srow) * 1024 + k0 + half * 16;
            float4 a0 = *(const float4*)(p + 0);
            float4 a1 = *(const float4*)(p + 4);
            float4 a2 = *(const float4*)(p + 8);
            float4 a3 = *(const float4*)(p + 12);
            uint4 w0 = make_uint4(packtr(a0.x, a0.y), packtr(a0.z, a0.w),
                                  packtr(a1.x, a1.y), packtr(a1.z, a1.w));
            uint4 w1 = make_uint4(packtr(a2.x, a2.y), packtr(a2.z, a2.w),
                                  packtr(a3.x, a3.y), packtr(a3.z, a3.w));
            const int c8 = half * 2;
            *(uint4*)&As[srow][sw32(srow, c8)]     = w0;
            *(uint4*)&As[srow][sw32(srow, c8 + 1)] = w1;
            // B: one b128 per thread
            *(uint4*)&Bs[brow][sw32(brow, bc8)] =
                *(const uint4*)(WT + (size_t)(n0 + brow) * 1024 + k0 + bc8 * 8);
        }
        __syncthreads();
        bf16x8 af[4], bfr[2];
        #pragma unroll
        for (int mt = 0; mt < 4; ++mt) {
            const int r = wm + mt * 16 + l16;
            af[mt] = *(const bf16x8*)&As[r][sw32(r, quad)];
        }
        #pragma unroll
        for (int nt = 0; nt < 2; ++nt) {
            const int r = wn + nt * 16 + l16;
            bfr[nt] = *(const bf16x8*)&Bs[r][sw32(r, quad)];
        }
        #pragma unroll
        for (int mt = 0; mt < 4; ++mt)
            #pragma unroll
            for (int nt = 0; nt < 2; ++nt)
                acc[mt][nt] = __builtin_amdgcn_mfma_f32_16x16x32_bf16(
                    af[mt], bfr[nt], acc[mt][nt], 0, 0, 0);
    }

    #pragma unroll
    for (int nt = 0; nt < 2; ++nt) {
        const int col = n0 + wn + nt * 16 + l16;
        const float bv = bias[col];
        #pragma unroll
        for (int mt = 0; mt < 4; ++mt) {
            #pragma unroll
            for (int r = 0; r < 4; ++r) {
                const int row = m0 + wm + mt * 16 + quad * 4 + r;
                float v = acc[mt][nt][r] + bv;
                if (neg && row >= 2048) v = -v;
                Y[(size_t)row * 1024 + col] = f2bf(v);
            }
        }
    }
}

// ---------------- output GEMM: d_out = Cc(bf16) . WoT^T + bo, f32 out ---------
__global__ __launch_bounds__(256) void gemm_out(
    const u16* __restrict__ X, const u16* __restrict__ WT,
    const float* __restrict__ bias, float* __restrict__ Y)
{
    __shared__ __attribute__((aligned(16))) u16 As[128][32];
    __shared__ __attribute__((aligned(16))) u16 Bs[64][32];
    const int tid = threadIdx.x;
    const int lane = tid & 63;
    const int wave = tid >> 6;
    const int quad = lane >> 4;
    const int l16 = lane & 15;
    const int m0 = blockIdx.x * 128;
    const int n0 = blockIdx.y * 64;
    const int wm = (wave & 1) * 64, wn = (wave >> 1) * 32;

    const int srow = tid >> 1, half = tid & 1;
    const int brow = tid >> 2, bc8 = tid & 3;

    f32x4 acc[4][2] = {};

    for (int k0 = 0; k0 < 1024; k0 += 32) {
        __syncthreads();
        {
            const u16* p = X + (size_t)(m0 + srow) * 1024 + k0 + half * 16;
            const int c8 = half * 2;
            *(uint4*)&As[srow][sw32(srow, c8)]     = *(const uint4*)p;
            *(uint4*)&As[srow][sw32(srow, c8 + 1)] = *(const uint4*)(p + 8);
            *(uint4*)&Bs[brow][sw32(brow, bc8)] =
                *(const uint4*)(WT + (size_t)(n0 + brow) * 1024 + k0 + bc8 * 8);
        }
        __syncthreads();
        bf16x8 af[4], bfr[2];
        #pragma unroll
        for (int mt = 0; mt < 4; ++mt) {
            const int r = wm + mt * 16 + l16;
            af[mt] = *(const bf16x8*)&As[r][sw32(r, quad)];
        }
        #pragma unroll
        for (int nt = 0; nt < 2; ++nt) {
            const int r = wn + nt * 16 + l16;
            bfr[nt] = *(const bf16x8*)&Bs[r][sw32(r, quad)];
        }
        #pragma unroll
        for (int mt = 0; mt < 4; ++mt)
            #pragma unroll
            for (int nt = 0; nt < 2; ++nt)
                acc[mt][nt] = __builtin_amdgcn_mfma_f32_16x16x32_bf16(
                    af[mt], bfr[nt], acc[mt][nt], 0, 0, 0);
    }

    #pragma unroll
    for (int nt = 0; nt < 2; ++nt) {
        const int col = n0 + wn + nt * 16 + l16;
        const float bv = bias[col];
        #pragma unroll
        for (int mt = 0; mt < 4; ++mt) {
            #pragma unroll
            for (int r = 0; r < 4; ++r) {
                const int row = m0 + wm + mt * 16 + quad * 4 + r;
                Y[(size_t)row * 1024 + col] = acc[mt][nt][r] + bv;
            }
        }
    }
}

// ---------------- fused MFMA attention, batch-axis softmax --------------------
// Kp holds K0 and -K1  =>  dacc = Q0.K0^T - Q1.K1^T (one acc set).
// P0 = sigmoid(dacc/8); O0 = P0.V0; O1 = csums - P0.V1.
// Swizzled LDS (conflict-free), XCD head-grouping block swizzle.
__global__ __launch_bounds__(256) void attn_mfma(
    const u16* __restrict__ Qb, const u16* __restrict__ Kb,
    const u16* __restrict__ VT, const float* __restrict__ csums,
    u16* __restrict__ Cc)
{
    __shared__ __attribute__((aligned(16))) u16 Ks[2][64][64];  // [b][t][dk] swz
    __shared__ __attribute__((aligned(16))) u16 Vs[2][64][64];  // [b][dk][t] swz
    __shared__ __attribute__((aligned(16))) u16 Ps[64][64];     // [s][t]   swz

    const int id = blockIdx.x;              // 0..511
    const int xcd = id & 7, j = id >> 3;
    const int h = xcd + 8 * (j >> 5);       // same h -> same XCD (round-robin heuristic)
    const int s0 = (j & 31) * 64;

    const int tid = threadIdx.x;
    const int lane = tid & 63;
    const int wave = tid >> 6;
    const int quad = lane >> 4;
    const int l16 = lane & 15;
    const int sw = wave * 16;

    const int r_ = tid >> 2;
    const int cq = (tid & 3) * 16;
    const int cq8 = (tid & 3) * 2;

    // Q fragments straight from global (reused across all 32 t-iters)
    bf16x8 qf[2][2];
    #pragma unroll
    for (int b = 0; b < 2; ++b)
        #pragma unroll
        for (int ks = 0; ks < 2; ++ks)
            qf[b][ks] = *(const bf16x8*)(Qb + (size_t)(b * S_ + s0 + sw + l16) * 1024
                                          + h * 64 + ks * 32 + quad * 8);

    f32x4 O0[4] = {}, T1[4] = {};

    for (int t0 = 0; t0 < S_; t0 += 64) {
        __syncthreads();                       // prev iter's LDS reads done
        #pragma unroll
        for (int b = 0; b < 2; ++b) {
            const u16* pk = Kb + (size_t)(b * S_ + t0 + r_) * 1024 + h * 64 + cq;
            *(uint4*)&Ks[b][r_][sw64(r_, cq8)]     = *(const uint4*)pk;
            *(uint4*)&Ks[b][r_][sw64(r_, cq8 + 1)] = *(const uint4*)(pk + 8);
            const u16* pv = VT + ((size_t)(b * H_ + h) * 64 + r_) * 2048 + t0 + cq;
            *(uint4*)&Vs[b][r_][sw64(r_, cq8)]     = *(const uint4*)pv;
            *(uint4*)&Vs[b][r_][sw64(r_, cq8 + 1)] = *(const uint4*)(pv + 8);
        }
        __syncthreads();

        // ---- delta tiles: A = K rows (m=t), B = Q regs (n=s) ----
        f32x4 dacc[4] = {};
        #pragma unroll
        for (int mt = 0; mt < 4; ++mt) {
            const int kr = mt * 16 + l16;
            #pragma unroll
            for (int ks = 0; ks < 2; ++ks) {
                bf16x8 k0f = *(const bf16x8*)&Ks[0][kr][sw64(kr, ks * 4 + quad)];
                dacc[mt] = __builtin_amdgcn_mfma_f32_16x16x32_bf16(k0f, qf[0][ks], dacc[mt], 0, 0, 0);
                bf16x8 k1f = *(const bf16x8*)&Ks[1][kr][sw64(kr, ks * 4 + quad)];
                dacc[mt] = __builtin_amdgcn_mfma_f32_16x16x32_bf16(k1f, qf[1][ks], dacc[mt], 0, 0, 0);
            }
        }
        // ---- sigmoid + P store: row s = sw+l16, t = mt*16+quad*4+r ----
        const int pr = sw + l16;
        #pragma unroll
        for (int mt = 0; mt < 4; ++mt) {
            float p[4];
            #pragma unroll
            for (int r = 0; r < 4; ++r) {
                float e = __expf(dacc[mt][r] * -0.125f);
                p[r] = __builtin_amdgcn_rcpf(1.0f + e);
            }
            uint2 w;
            w.x = packtr(p[0], p[1]);
            w.y = packtr(p[2], p[3]);
            const int c8 = 2 * mt + (quad >> 1);
            *(uint2*)&Ps[pr][sw64(pr, c8) + (quad & 1) * 4] = w;
        }
        // ---- PV (wave-private P readback; lgkmcnt only, no barrier) ----
        bf16x8 pf0 = *(const bf16x8*)&Ps[pr][sw64(pr, quad)];
        bf16x8 pf1 = *(const bf16x8*)&Ps[pr][sw64(pr, 4 + quad)];
        #pragma unroll
        for (int nt = 0; nt < 4; ++nt) {
            const int vr = nt * 16 + l16;
            bf16x8 v00 = *(const bf16x8*)&Vs[0][vr][sw64(vr, quad)];
            bf16x8 v01 = *(const bf16x8*)&Vs[0][vr][sw64(vr, 4 + quad)];
            O0[nt] = __builtin_amdgcn_mfma_f32_16x16x32_bf16(pf0, v00, O0[nt], 0, 0, 0);
            O0[nt] = __builtin_amdgcn_mfma_f32_16x16x32_bf16(pf1, v01, O0[nt], 0, 0, 0);
            bf16x8 v10 = *(const bf16x8*)&Vs[1][vr][sw64(vr, quad)];
            bf16x8 v11 = *(const bf16x8*)&Vs[1][vr][sw64(vr, 4 + quad)];
            T1[nt] = __builtin_amdgcn_mfma_f32_16x16x32_bf16(pf0, v10, T1[nt], 0, 0, 0);
            T1[nt] = __builtin_amdgcn_mfma_f32_16x16x32_bf16(pf1, v11, T1[nt], 0, 0, 0);
        }
    }

    // ---- epilogue ----
    #pragma unroll
    for (int nt = 0; nt < 4; ++nt) {
        const int dk = nt * 16 + l16;
        const float cs1 = csums[h * 64 + dk];
        #pragma unroll
        for (int r = 0; r < 4; ++r) {
            const int s = s0 + sw + quad * 4 + r;
            Cc[(size_t)(0 * S_ + s) * 1024 + h * 64 + dk] = f2bf(O0[nt][r]);
            Cc[(size_t)(1 * S_ + s) * 1024 + h * 64 + dk] = f2bf(cs1 - T1[nt][r]);
        }
    }
}

extern "C" void kernel_launch(void* const* d_in, const int* in_sizes, int n_in,
                              void* d_out, int out_size, void* d_ws, size_t ws_size,
                              hipStream_t stream) {
    const float* q  = (const float*)d_in[0];
    const float* k  = (const float*)d_in[1];
    const float* v  = (const float*)d_in[2];
    const float* Wq = (const float*)d_in[3];
    const float* bq = (const float*)d_in[4];
    const float* Wk = (const float*)d_in[5];
    const float* bk = (const float*)d_in[6];
    const float* Wv = (const float*)d_in[7];
    const float* bv = (const float*)d_in[8];
    const float* Wo = (const float*)d_in[9];
    const float* bo = (const float*)d_in[10];

    char* ws = (char*)d_ws;
    const size_t MB = 1024 * 1024;
    u16* Cc  = (u16*)(ws);             // 8 MB
    u16* WqT = (u16*)(ws + 8  * MB);
    u16* WkT = (u16*)(ws + 10 * MB);
    u16* WvT = (u16*)(ws + 12 * MB);
    u16* WoT = (u16*)(ws + 14 * MB);
    u16* Qp  = (u16*)(ws + 16 * MB);
    u16* Kp  = (u16*)(ws + 24 * MB);
    u16* Vp  = (u16*)(ws + 32 * MB);
    u16* VTv = (u16*)(ws + 40 * MB);
    float* csums = (float*)d_out;      // scratch; gemm_out overwrites d_out

    dim3 blk(256);

    WArgs wa;
    wa.W[0] = Wq; wa.W[1] = Wk; wa.W[2] = Wv; wa.W[3] = Wo;
    wa.WT[0] = WqT; wa.WT[1] = WkT; wa.WT[2] = WvT; wa.WT[3] = WoT;
    prep_w<<<dim3(16, 16, 4), blk, 0, stream>>>(wa);

    ProjArgs pa;
    pa.X[0] = q;  pa.X[1] = k;  pa.X[2] = v;
    pa.W[0] = WqT; pa.W[1] = WkT; pa.W[2] = WvT;
    pa.bias[0] = bq; pa.bias[1] = bk; pa.bias[2] = bv;
    pa.Y[0] = Qp; pa.Y[1] = Kp; pa.Y[2] = Vp;
    proj3<<<dim3(32, 16, 3), blk, 0, stream>>>(pa);

    hipMemsetAsync(d_out, 0, 1024 * sizeof(float), stream);
    vprep<<<dim3(32, 32), blk, 0, stream>>>(Vp, VTv, csums);
    attn_mfma<<<dim3(512), blk, 0, stream>>>(Qp, Kp, VTv, csums, Cc);
    gemm_out<<<dim3(32, 16), blk, 0, stream>>>(Cc, WoT, bo, (float*)d_out);
}

// Round 7
// 259.182 us; speedup vs baseline: 1.8418x; 1.0667x over previous
//
#include <hip/hip_runtime.h>
#include <hip/hip_bf16.h>

#define B_ 2
#define S_ 2048
#define D_ 1024
#define H_ 16
#define DK_ 64
#define BS_ (B_ * S_)   // 4096

typedef unsigned int u32;
typedef unsigned short u16;
typedef __attribute__((ext_vector_type(8))) short bf16x8;
typedef __attribute__((ext_vector_type(4))) float f32x4;

__device__ __forceinline__ float bf2f(u16 v) {
    union { u32 u; float f; } c; c.u = ((u32)v) << 16; return c.f;
}
__device__ __forceinline__ u16 f2bf(float f) {   // RNE
    union { float f; u32 u; } c; c.f = f;
    u32 u = c.u;
    return (u16)((u + 0x7fffu + ((u >> 16) & 1u)) >> 16);
}
// truncating pack of two f32 -> bf16x2 in ONE v_perm (hot paths)
__device__ __forceinline__ u32 packtr(float lo, float hi) {
    union { float f; u32 u; } a, b; a.f = lo; b.f = hi;
    return __builtin_amdgcn_perm(b.u, a.u, 0x07060302u);
}
// LDS swizzle for attn (unpadded stride-64 tiles)
__device__ __forceinline__ int sw64(int r, int c8) { return (((c8) + (r)) & 7) * 8; }

// ---------------- weight transpose+convert: WT[n][k] bf16 (z picks matrix) ----
// Block (0,0,0) additionally zeroes csums (d_out scratch) before vprep's atomics.
struct WArgs { const float* W[4]; u16* WT[4]; float* csums; };
__global__ __launch_bounds__(256) void prep_w(WArgs wa)
{
    __shared__ __attribute__((aligned(16))) u16 T[64][72];
    const int z = blockIdx.z;
    const float* W = wa.W[z];
    u16* WT = wa.WT[z];
    const int headMode = (z < 3) ? 1 : 0;
    const int tid = threadIdx.x;
    if (z == 0 && blockIdx.x == 0 && blockIdx.y == 0) {
        float4 zz = {0.f, 0.f, 0.f, 0.f};
        *(float4*)(wa.csums + tid * 4) = zz;   // 256*16B = 4KB = 1024 floats
    }
    const int k0 = blockIdx.x * 64;
    const int n0 = blockIdx.y * 64;
    const int kr = tid >> 4;
    const int n4 = (tid & 15) * 4;
    #pragma unroll
    for (int pass = 0; pass < 4; ++pass) {
        int kk = k0 + pass * 16 + kr;
        const float* p = headMode
            ? (W + (size_t)((n0 + n4) >> 6) * (1024 * 64) + kk * 64 + ((n0 + n4) & 63))
            : (W + (size_t)kk * 1024 + n0 + n4);
        float4 a = *(const float4*)p;
        int krel = pass * 16 + kr;
        T[n4 + 0][krel] = f2bf(a.x);
        T[n4 + 1][krel] = f2bf(a.y);
        T[n4 + 2][krel] = f2bf(a.z);
        T[n4 + 3][krel] = f2bf(a.w);
    }
    __syncthreads();
    const int nr = tid >> 2;
    const int kq = (tid & 3) * 16;
    uint4 o0 = *(const uint4*)&T[nr][kq];
    uint4 o1 = *(const uint4*)&T[nr][kq + 8];
    u16* q = WT + (size_t)(n0 + nr) * 1024 + k0 + kq;
    *(uint4*)q = o0;
    *(uint4*)(q + 8) = o1;
}

// ---------------- V transpose + fused colsum(V1): VT[b][h][dk][t] -------------
__global__ __launch_bounds__(256) void vprep(
    const u16* __restrict__ Vb, u16* __restrict__ VT, float* __restrict__ csums)
{
    __shared__ __attribute__((aligned(16))) u16 T[64][72];
    __shared__ float red[256];
    const int tid = threadIdx.x;
    const int t0 = blockIdx.x * 64;
    const int bh = blockIdx.y;
    const int b = bh >> 4, h = bh & 15;
    const int tr = tid >> 4;
    const int d4 = (tid & 15) * 4;
    #pragma unroll
    for (int pass = 0; pass < 4; ++pass) {
        int tt = t0 + pass * 16 + tr;
        const u16* p = Vb + (size_t)(b * S_ + tt) * 1024 + h * 64 + d4;
        u32 a = *(const u32*)p;
        u32 c = *(const u32*)(p + 2);
        int trel = pass * 16 + tr;
        T[d4 + 0][trel] = (u16)a;
        T[d4 + 1][trel] = (u16)(a >> 16);
        T[d4 + 2][trel] = (u16)c;
        T[d4 + 3][trel] = (u16)(c >> 16);
    }
    __syncthreads();
    const int dr = tid >> 2;
    const int tq = (tid & 3) * 16;
    uint4 o0 = *(const uint4*)&T[dr][tq];
    uint4 o1 = *(const uint4*)&T[dr][tq + 8];
    u16* q = VT + ((size_t)bh * 64 + dr) * 2048 + t0 + tq;
    *(uint4*)q = o0;
    *(uint4*)(q + 8) = o1;

    if (b == 1) {   // fused colsum of V batch-1
        const int dk = tid & 63, part = tid >> 6;
        float s = 0.f;
        #pragma unroll
        for (int t = 0; t < 16; ++t) s += bf2f(T[dk][part * 16 + t]);
        red[tid] = s;
        __syncthreads();
        if (tid < 64)
            atomicAdd(&csums[h * 64 + tid],
                      red[tid] + red[tid + 64] + red[tid + 128] + red[tid + 192]);
    }
}

// ---------------- fused projections: Y = X(f32) . WT^T + bias, bf16 out -------
// 128x128 tile, BK=64, 4 waves 64x64, z in {q,k,v}; z==1 negates rows >= 2048.
struct ProjArgs {
    const float* X[3];
    const u16* W[3];
    const float* bias[3];
    u16* Y[3];
};
__global__ __launch_bounds__(256) void proj3(ProjArgs pa)
{
    __shared__ __attribute__((aligned(16))) u16 As[128][72];
    __shared__ __attribute__((aligned(16))) u16 Bs[128][72];
    const int z = blockIdx.z;
    const float* X = pa.X[z];
    const u16* WT = pa.W[z];
    const float* bias = pa.bias[z];
    u16* Y = pa.Y[z];
    const int neg = (z == 1);

    const int tid = threadIdx.x;
    const int lane = tid & 63;
    const int wave = tid >> 6;
    const int quad = lane >> 4;
    const int l16 = lane & 15;
    const int m0 = blockIdx.x * 128;
    const int n0 = blockIdx.y * 128;
    const int wm = (wave & 1) * 64, wn = (wave >> 1) * 64;

    const int srow = tid >> 1;          // 0..127
    const int scol = (tid & 1) * 32;    // u16 col: 0 or 32

    f32x4 acc[4][4] = {};

    for (int k0 = 0; k0 < 1024; k0 += 64) {
        __syncthreads();
        {   // A: f32 -> bf16 convert fused into staging (32 u16 per thread)
            const float* p = X + (size_t)(m0 + srow) * 1024 + k0 + scol;
            #pragma unroll
            for (int j = 0; j < 2; ++j) {
                float4 a0 = *(const float4*)(p + j * 16 + 0);
                float4 a1 = *(const float4*)(p + j * 16 + 4);
                float4 a2 = *(const float4*)(p + j * 16 + 8);
                float4 a3 = *(const float4*)(p + j * 16 + 12);
                uint4 w0 = make_uint4(packtr(a0.x, a0.y), packtr(a0.z, a0.w),
                                      packtr(a1.x, a1.y), packtr(a1.z, a1.w));
                uint4 w1 = make_uint4(packtr(a2.x, a2.y), packtr(a2.z, a2.w),
                                      packtr(a3.x, a3.y), packtr(a3.z, a3.w));
                *(uint4*)&As[srow][scol + j * 16]     = w0;
                *(uint4*)&As[srow][scol + j * 16 + 8] = w1;
            }
            // B: bf16, 32 u16 per thread
            const u16* q = WT + (size_t)(n0 + srow) * 1024 + k0 + scol;
            #pragma unroll
            for (int j = 0; j < 4; ++j)
                *(uint4*)&Bs[srow][scol + j * 8] = *(const uint4*)(q + j * 8);
        }
        __syncthreads();
        #pragma unroll
        for (int ks = 0; ks < 2; ++ks) {
            bf16x8 af[4], bfr[4];
            #pragma unroll
            for (int mt = 0; mt < 4; ++mt)
                af[mt] = *(const bf16x8*)&As[wm + mt * 16 + l16][ks * 32 + quad * 8];
            #pragma unroll
            for (int nt = 0; nt < 4; ++nt)
                bfr[nt] = *(const bf16x8*)&Bs[wn + nt * 16 + l16][ks * 32 + quad * 8];
            #pragma unroll
            for (int mt = 0; mt < 4; ++mt)
                #pragma unroll
                for (int nt = 0; nt < 4; ++nt)
                    acc[mt][nt] = __builtin_amdgcn_mfma_f32_16x16x32_bf16(
                        af[mt], bfr[nt], acc[mt][nt], 0, 0, 0);
        }
    }

    #pragma unroll
    for (int nt = 0; nt < 4; ++nt) {
        const int col = n0 + wn + nt * 16 + l16;
        const float bv = bias[col];
        #pragma unroll
        for (int mt = 0; mt < 4; ++mt) {
            #pragma unroll
            for (int r = 0; r < 4; ++r) {
                const int row = m0 + wm + mt * 16 + quad * 4 + r;
                float v = acc[mt][nt][r] + bv;
                if (neg && row >= 2048) v = -v;
                Y[(size_t)row * 1024 + col] = f2bf(v);
            }
        }
    }
}

// ---------------- output GEMM: d_out = Cc(bf16) . WoT^T + bo, f32 out ---------
// 128x64 tile, BK=64, grid 32x16 = 512 blocks (2/CU).
__global__ __launch_bounds__(256) void gemm_out(
    const u16* __restrict__ X, const u16* __restrict__ WT,
    const float* __restrict__ bias, float* __restrict__ Y)
{
    __shared__ __attribute__((aligned(16))) u16 As[128][72];
    __shared__ __attribute__((aligned(16))) u16 Bs[64][72];
    const int tid = threadIdx.x;
    const int lane = tid & 63;
    const int wave = tid >> 6;
    const int quad = lane >> 4;
    const int l16 = lane & 15;
    const int m0 = blockIdx.x * 128;
    const int n0 = blockIdx.y * 64;
    const int wm = (wave & 1) * 64, wn = (wave >> 1) * 32;

    const int srow = tid >> 1;          // A: 0..127
    const int scol = (tid & 1) * 32;
    const int brow = tid >> 2;          // B: 0..63
    const int bcol = (tid & 3) * 16;

    f32x4 acc[4][2] = {};

    for (int k0 = 0; k0 < 1024; k0 += 64) {
        __syncthreads();
        {
            const u16* p = X + (size_t)(m0 + srow) * 1024 + k0 + scol;
            #pragma unroll
            for (int j = 0; j < 4; ++j)
                *(uint4*)&As[srow][scol + j * 8] = *(const uint4*)(p + j * 8);
            const u16* q = WT + (size_t)(n0 + brow) * 1024 + k0 + bcol;
            *(uint4*)&Bs[brow][bcol]     = *(const uint4*)q;
            *(uint4*)&Bs[brow][bcol + 8] = *(const uint4*)(q + 8);
        }
        __syncthreads();
        #pragma unroll
        for (int ks = 0; ks < 2; ++ks) {
            bf16x8 af[4], bfr[2];
            #pragma unroll
            for (int mt = 0; mt < 4; ++mt)
                af[mt] = *(const bf16x8*)&As[wm + mt * 16 + l16][ks * 32 + quad * 8];
            #pragma unroll
            for (int nt = 0; nt < 2; ++nt)
                bfr[nt] = *(const bf16x8*)&Bs[wn + nt * 16 + l16][ks * 32 + quad * 8];
            #pragma unroll
            for (int mt = 0; mt < 4; ++mt)
                #pragma unroll
                for (int nt = 0; nt < 2; ++nt)
                    acc[mt][nt] = __builtin_amdgcn_mfma_f32_16x16x32_bf16(
                        af[mt], bfr[nt], acc[mt][nt], 0, 0, 0);
        }
    }

    #pragma unroll
    for (int nt = 0; nt < 2; ++nt) {
        const int col = n0 + wn + nt * 16 + l16;
        const float bv = bias[col];
        #pragma unroll
        for (int mt = 0; mt < 4; ++mt) {
            #pragma unroll
            for (int r = 0; r < 4; ++r) {
                const int row = m0 + wm + mt * 16 + quad * 4 + r;
                Y[(size_t)row * 1024 + col] = acc[mt][nt][r] + bv;
            }
        }
    }
}

// ---------------- fused MFMA attention (unchanged from round 6) ---------------
__global__ __launch_bounds__(256) void attn_mfma(
    const u16* __restrict__ Qb, const u16* __restrict__ Kb,
    const u16* __restrict__ VT, const float* __restrict__ csums,
    u16* __restrict__ Cc)
{
    __shared__ __attribute__((aligned(16))) u16 Ks[2][64][64];
    __shared__ __attribute__((aligned(16))) u16 Vs[2][64][64];
    __shared__ __attribute__((aligned(16))) u16 Ps[64][64];

    const int id = blockIdx.x;              // 0..511
    const int xcd = id & 7, j = id >> 3;
    const int h = xcd + 8 * (j >> 5);
    const int s0 = (j & 31) * 64;

    const int tid = threadIdx.x;
    const int lane = tid & 63;
    const int wave = tid >> 6;
    const int quad = lane >> 4;
    const int l16 = lane & 15;
    const int sw = wave * 16;

    const int r_ = tid >> 2;
    const int cq = (tid & 3) * 16;
    const int cq8 = (tid & 3) * 2;

    bf16x8 qf[2][2];
    #pragma unroll
    for (int b = 0; b < 2; ++b)
        #pragma unroll
        for (int ks = 0; ks < 2; ++ks)
            qf[b][ks] = *(const bf16x8*)(Qb + (size_t)(b * S_ + s0 + sw + l16) * 1024
                                          + h * 64 + ks * 32 + quad * 8);

    f32x4 O0[4] = {}, T1[4] = {};

    for (int t0 = 0; t0 < S_; t0 += 64) {
        __syncthreads();
        #pragma unroll
        for (int b = 0; b < 2; ++b) {
            const u16* pk = Kb + (size_t)(b * S_ + t0 + r_) * 1024 + h * 64 + cq;
            *(uint4*)&Ks[b][r_][sw64(r_, cq8)]     = *(const uint4*)pk;
            *(uint4*)&Ks[b][r_][sw64(r_, cq8 + 1)] = *(const uint4*)(pk + 8);
            const u16* pv = VT + ((size_t)(b * H_ + h) * 64 + r_) * 2048 + t0 + cq;
            *(uint4*)&Vs[b][r_][sw64(r_, cq8)]     = *(const uint4*)pv;
            *(uint4*)&Vs[b][r_][sw64(r_, cq8 + 1)] = *(const uint4*)(pv + 8);
        }
        __syncthreads();

        f32x4 dacc[4] = {};
        #pragma unroll
        for (int mt = 0; mt < 4; ++mt) {
            const int kr = mt * 16 + l16;
            #pragma unroll
            for (int ks = 0; ks < 2; ++ks) {
                bf16x8 k0f = *(const bf16x8*)&Ks[0][kr][sw64(kr, ks * 4 + quad)];
                dacc[mt] = __builtin_amdgcn_mfma_f32_16x16x32_bf16(k0f, qf[0][ks], dacc[mt], 0, 0, 0);
                bf16x8 k1f = *(const bf16x8*)&Ks[1][kr][sw64(kr, ks * 4 + quad)];
                dacc[mt] = __builtin_amdgcn_mfma_f32_16x16x32_bf16(k1f, qf[1][ks], dacc[mt], 0, 0, 0);
            }
        }
        const int pr = sw + l16;
        #pragma unroll
        for (int mt = 0; mt < 4; ++mt) {
            float p[4];
            #pragma unroll
            for (int r = 0; r < 4; ++r) {
                float e = __expf(dacc[mt][r] * -0.125f);
                p[r] = __builtin_amdgcn_rcpf(1.0f + e);
            }
            uint2 w;
            w.x = packtr(p[0], p[1]);
            w.y = packtr(p[2], p[3]);
            const int c8 = 2 * mt + (quad >> 1);
            *(uint2*)&Ps[pr][sw64(pr, c8) + (quad & 1) * 4] = w;
        }
        bf16x8 pf0 = *(const bf16x8*)&Ps[pr][sw64(pr, quad)];
        bf16x8 pf1 = *(const bf16x8*)&Ps[pr][sw64(pr, 4 + quad)];
        #pragma unroll
        for (int nt = 0; nt < 4; ++nt) {
            const int vr = nt * 16 + l16;
            bf16x8 v00 = *(const bf16x8*)&Vs[0][vr][sw64(vr, quad)];
            bf16x8 v01 = *(const bf16x8*)&Vs[0][vr][sw64(vr, 4 + quad)];
            O0[nt] = __builtin_amdgcn_mfma_f32_16x16x32_bf16(pf0, v00, O0[nt], 0, 0, 0);
            O0[nt] = __builtin_amdgcn_mfma_f32_16x16x32_bf16(pf1, v01, O0[nt], 0, 0, 0);
            bf16x8 v10 = *(const bf16x8*)&Vs[1][vr][sw64(vr, quad)];
            bf16x8 v11 = *(const bf16x8*)&Vs[1][vr][sw64(vr, 4 + quad)];
            T1[nt] = __builtin_amdgcn_mfma_f32_16x16x32_bf16(pf0, v10, T1[nt], 0, 0, 0);
            T1[nt] = __builtin_amdgcn_mfma_f32_16x16x32_bf16(pf1, v11, T1[nt], 0, 0, 0);
        }
    }

    #pragma unroll
    for (int nt = 0; nt < 4; ++nt) {
        const int dk = nt * 16 + l16;
        const float cs1 = csums[h * 64 + dk];
        #pragma unroll
        for (int r = 0; r < 4; ++r) {
            const int s = s0 + sw + quad * 4 + r;
            Cc[(size_t)(0 * S_ + s) * 1024 + h * 64 + dk] = f2bf(O0[nt][r]);
            Cc[(size_t)(1 * S_ + s) * 1024 + h * 64 + dk] = f2bf(cs1 - T1[nt][r]);
        }
    }
}

extern "C" void kernel_launch(void* const* d_in, const int* in_sizes, int n_in,
                              void* d_out, int out_size, void* d_ws, size_t ws_size,
                              hipStream_t stream) {
    const float* q  = (const float*)d_in[0];
    const float* k  = (const float*)d_in[1];
    const float* v  = (const float*)d_in[2];
    const float* Wq = (const float*)d_in[3];
    const float* bq = (const float*)d_in[4];
    const float* Wk = (const float*)d_in[5];
    const float* bk = (const float*)d_in[6];
    const float* Wv = (const float*)d_in[7];
    const float* bv = (const float*)d_in[8];
    const float* Wo = (const float*)d_in[9];
    const float* bo = (const float*)d_in[10];

    char* ws = (char*)d_ws;
    const size_t MB = 1024 * 1024;
    u16* Cc  = (u16*)(ws);
    u16* WqT = (u16*)(ws + 8  * MB);
    u16* WkT = (u16*)(ws + 10 * MB);
    u16* WvT = (u16*)(ws + 12 * MB);
    u16* WoT = (u16*)(ws + 14 * MB);
    u16* Qp  = (u16*)(ws + 16 * MB);
    u16* Kp  = (u16*)(ws + 24 * MB);
    u16* Vp  = (u16*)(ws + 32 * MB);
    u16* VTv = (u16*)(ws + 40 * MB);
    float* csums = (float*)d_out;      // scratch; gemm_out overwrites d_out last

    dim3 blk(256);

    WArgs wa;
    wa.W[0] = Wq; wa.W[1] = Wk; wa.W[2] = Wv; wa.W[3] = Wo;
    wa.WT[0] = WqT; wa.WT[1] = WkT; wa.WT[2] = WvT; wa.WT[3] = WoT;
    wa.csums = csums;
    prep_w<<<dim3(16, 16, 4), blk, 0, stream>>>(wa);

    ProjArgs pa;
    pa.X[0] = q;  pa.X[1] = k;  pa.X[2] = v;
    pa.W[0] = WqT; pa.W[1] = WkT; pa.W[2] = WvT;
    pa.bias[0] = bq; pa.bias[1] = bk; pa.bias[2] = bv;
    pa.Y[0] = Qp; pa.Y[1] = Kp; pa.Y[2] = Vp;
    proj3<<<dim3(32, 8, 3), blk, 0, stream>>>(pa);

    vprep<<<dim3(32, 32), blk, 0, stream>>>(Vp, VTv, csums);
    attn_mfma<<<dim3(512), blk, 0, stream>>>(Qp, Kp, VTv, csums, Cc);
    gemm_out<<<dim3(32, 16), blk, 0, stream>>>(Cc, WoT, bo, (float*)d_out);
}

// Round 8
// 239.710 us; speedup vs baseline: 1.9914x; 1.0812x over previous
//
#include <hip/hip_runtime.h>
#include <hip/hip_bf16.h>

#define B_ 2
#define S_ 2048
#define D_ 1024
#define H_ 16
#define DK_ 64
#define BS_ (B_ * S_)   // 4096

typedef unsigned int u32;
typedef unsigned short u16;
typedef __attribute__((ext_vector_type(8))) short bf16x8;
typedef __attribute__((ext_vector_type(4))) float f32x4;

typedef const __attribute__((address_space(1))) void glb_cv;
typedef __attribute__((address_space(3))) void lds_v;

__device__ __forceinline__ void async_cp16(const void* g, void* l) {
    __builtin_amdgcn_global_load_lds((glb_cv*)g, (lds_v*)l, 16, 0, 0);
}

__device__ __forceinline__ float bf2f(u16 v) {
    union { u32 u; float f; } c; c.u = ((u32)v) << 16; return c.f;
}
__device__ __forceinline__ u16 f2bf(float f) {   // RNE
    union { float f; u32 u; } c; c.f = f;
    u32 u = c.u;
    return (u16)((u + 0x7fffu + ((u >> 16) & 1u)) >> 16);
}
__device__ __forceinline__ u32 pack2(float a, float b) {
    return (u32)f2bf(a) | ((u32)f2bf(b) << 16);
}
// truncating pack (hot attn path only)
__device__ __forceinline__ u32 packtr(float lo, float hi) {
    union { float f; u32 u; } a, b; a.f = lo; b.f = hi;
    return __builtin_amdgcn_perm(b.u, a.u, 0x07060302u);
}
// LDS swizzle for attn tiles
__device__ __forceinline__ int sw64(int r, int c8) { return (((c8) + (r)) & 7) * 8; }

// ------------- fused prep: weight transposes + X f32->bf16 + csums zero ------
// blocks [0,1024): weight transpose (z = id>>8); blocks [1024,7168): X convert.
struct PrepArgs {
    const float* W[4]; u16* WT[4];
    const float* X[3]; u16* XB[3];
    float* csums;
};
__global__ __launch_bounds__(256) void prep(PrepArgs a)
{
    const int id = blockIdx.x;
    const int tid = threadIdx.x;
    if (id >= 1024) {   // ---- X convert: 2048 elems/block ----
        const int cid = id - 1024;
        const int z = cid >> 11;
        const size_t base = (size_t)(cid & 2047) * 2048 + tid * 8;
        const float* X = a.X[z];
        float4 x0 = *(const float4*)(X + base);
        float4 x1 = *(const float4*)(X + base + 4);
        uint4 o;
        o.x = pack2(x0.x, x0.y); o.y = pack2(x0.z, x0.w);
        o.z = pack2(x1.x, x1.y); o.w = pack2(x1.z, x1.w);
        *(uint4*)(a.XB[z] + base) = o;
        return;
    }
    if (id == 0) {      // csums zero (1024 floats)
        float4 zz = {0.f, 0.f, 0.f, 0.f};
        *(float4*)(a.csums + tid * 4) = zz;
    }
    __shared__ __attribute__((aligned(16))) u16 T[64][72];
    const int z = id >> 8;
    const int rem = id & 255;
    const float* W = a.W[z];
    u16* WT = a.WT[z];
    const int headMode = (z < 3) ? 1 : 0;
    const int k0 = (rem >> 4) * 64;
    const int n0 = (rem & 15) * 64;
    const int kr = tid >> 4;
    const int n4 = (tid & 15) * 4;
    #pragma unroll
    for (int pass = 0; pass < 4; ++pass) {
        int kk = k0 + pass * 16 + kr;
        const float* p = headMode
            ? (W + (size_t)((n0 + n4) >> 6) * (1024 * 64) + kk * 64 + ((n0 + n4) & 63))
            : (W + (size_t)kk * 1024 + n0 + n4);
        float4 v = *(const float4*)p;
        int krel = pass * 16 + kr;
        T[n4 + 0][krel] = f2bf(v.x);
        T[n4 + 1][krel] = f2bf(v.y);
        T[n4 + 2][krel] = f2bf(v.z);
        T[n4 + 3][krel] = f2bf(v.w);
    }
    __syncthreads();
    const int nr = tid >> 2;
    const int kq = (tid & 3) * 16;
    uint4 o0 = *(const uint4*)&T[nr][kq];
    uint4 o1 = *(const uint4*)&T[nr][kq + 8];
    u16* q = WT + (size_t)(n0 + nr) * 1024 + k0 + kq;
    *(uint4*)q = o0;
    *(uint4*)(q + 8) = o1;
}

// ---------------- V transpose + fused colsum(V1): VT[b][h][dk][t] -------------
__global__ __launch_bounds__(256) void vprep(
    const u16* __restrict__ Vb, u16* __restrict__ VT, float* __restrict__ csums)
{
    __shared__ __attribute__((aligned(16))) u16 T[64][72];
    __shared__ float red[256];
    const int tid = threadIdx.x;
    const int t0 = blockIdx.x * 64;
    const int bh = blockIdx.y;
    const int b = bh >> 4, h = bh & 15;
    const int tr = tid >> 4;
    const int d4 = (tid & 15) * 4;
    #pragma unroll
    for (int pass = 0; pass < 4; ++pass) {
        int tt = t0 + pass * 16 + tr;
        const u16* p = Vb + (size_t)(b * S_ + tt) * 1024 + h * 64 + d4;
        u32 a = *(const u32*)p;
        u32 c = *(const u32*)(p + 2);
        int trel = pass * 16 + tr;
        T[d4 + 0][trel] = (u16)a;
        T[d4 + 1][trel] = (u16)(a >> 16);
        T[d4 + 2][trel] = (u16)c;
        T[d4 + 3][trel] = (u16)(c >> 16);
    }
    __syncthreads();
    const int dr = tid >> 2;
    const int tq = (tid & 3) * 16;
    uint4 o0 = *(const uint4*)&T[dr][tq];
    uint4 o1 = *(const uint4*)&T[dr][tq + 8];
    u16* q = VT + ((size_t)bh * 64 + dr) * 2048 + t0 + tq;
    *(uint4*)q = o0;
    *(uint4*)(q + 8) = o1;

    if (b == 1) {
        const int dk = tid & 63, part = tid >> 6;
        float s = 0.f;
        #pragma unroll
        for (int t = 0; t < 16; ++t) s += bf2f(T[dk][part * 16 + t]);
        red[tid] = s;
        __syncthreads();
        if (tid < 64)
            atomicAdd(&csums[h * 64 + tid],
                      red[tid] + red[tid + 64] + red[tid + 128] + red[tid + 192]);
    }
}

// ---------------- fused projections (m97-style async staging) -----------------
// Y = XB(bf16) . WT^T + bias; 128x128 tile, BK=32, global_load_lds staging.
// z in {q,k,v}; z==1 negates rows >= 2048 (K batch-1 sign fold).
struct ProjArgs {
    const u16* X[3];
    const u16* W[3];
    const float* bias[3];
    u16* Y[3];
};
__global__ __launch_bounds__(256) void proj3(ProjArgs pa)
{
    __shared__ __attribute__((aligned(16))) u16 As[128][32];
    __shared__ __attribute__((aligned(16))) u16 Bs[128][32];
    const int z = blockIdx.z;
    const u16* X = pa.X[z];
    const u16* WT = pa.W[z];
    const float* bias = pa.bias[z];
    u16* Y = pa.Y[z];
    const int neg = (z == 1);

    const int tid = threadIdx.x;
    const int lane = tid & 63;
    const int wave = tid >> 6;
    const int quad = lane >> 4;
    const int l16 = lane & 15;
    const int m0 = blockIdx.x * 128;
    const int n0 = blockIdx.y * 128;
    const int wm = (wave & 1) * 64, wn = (wave >> 1) * 64;

    f32x4 acc[4][4] = {};

    for (int k0 = 0; k0 < 1024; k0 += 32) {
        __syncthreads();   // prior iter's frag reads done
        #pragma unroll
        for (int call = 0; call < 2; ++call) {
            const int c = tid + call * 256;               // chunk 0..511 (16B each)
            const int row = c >> 2, cc = (c & 3) * 8;     // [row][cc..cc+7]
            char* la = (char*)&As[0][0] + (size_t)(c & ~63) * 16;
            async_cp16(X + (size_t)(m0 + row) * 1024 + k0 + cc, la);
            char* lb = (char*)&Bs[0][0] + (size_t)(c & ~63) * 16;
            async_cp16(WT + (size_t)(n0 + row) * 1024 + k0 + cc, lb);
        }
        __syncthreads();   // drains vmcnt(0): LDS tiles ready

        bf16x8 af[4], bfr[4];
        #pragma unroll
        for (int mt = 0; mt < 4; ++mt)
            af[mt] = *(const bf16x8*)&As[wm + mt * 16 + l16][quad * 8];
        #pragma unroll
        for (int nt = 0; nt < 4; ++nt)
            bfr[nt] = *(const bf16x8*)&Bs[wn + nt * 16 + l16][quad * 8];
        #pragma unroll
        for (int mt = 0; mt < 4; ++mt)
            #pragma unroll
            for (int nt = 0; nt < 4; ++nt)
                acc[mt][nt] = __builtin_amdgcn_mfma_f32_16x16x32_bf16(
                    af[mt], bfr[nt], acc[mt][nt], 0, 0, 0);
    }

    #pragma unroll
    for (int nt = 0; nt < 4; ++nt) {
        const int col = n0 + wn + nt * 16 + l16;
        const float bv = bias[col];
        #pragma unroll
        for (int mt = 0; mt < 4; ++mt) {
            #pragma unroll
            for (int r = 0; r < 4; ++r) {
                const int row = m0 + wm + mt * 16 + quad * 4 + r;
                float v = acc[mt][nt][r] + bv;
                if (neg && row >= 2048) v = -v;
                Y[(size_t)row * 1024 + col] = f2bf(v);
            }
        }
    }
}

// ---------------- output GEMM (async staging): d_out = Cc . WoT^T + bo --------
// 128x64 tile, BK=32, grid 32x16 = 512 blocks.
__global__ __launch_bounds__(256) void gemm_out(
    const u16* __restrict__ X, const u16* __restrict__ WT,
    const float* __restrict__ bias, float* __restrict__ Y)
{
    __shared__ __attribute__((aligned(16))) u16 As[128][32];
    __shared__ __attribute__((aligned(16))) u16 Bs[64][32];
    const int tid = threadIdx.x;
    const int lane = tid & 63;
    const int wave = tid >> 6;
    const int quad = lane >> 4;
    const int l16 = lane & 15;
    const int m0 = blockIdx.x * 128;
    const int n0 = blockIdx.y * 64;
    const int wm = (wave & 1) * 64, wn = (wave >> 1) * 32;

    f32x4 acc[4][2] = {};

    for (int k0 = 0; k0 < 1024; k0 += 32) {
        __syncthreads();
        #pragma unroll
        for (int call = 0; call < 2; ++call) {
            const int c = tid + call * 256;
            const int row = c >> 2, cc = (c & 3) * 8;
            char* la = (char*)&As[0][0] + (size_t)(c & ~63) * 16;
            async_cp16(X + (size_t)(m0 + row) * 1024 + k0 + cc, la);
        }
        {
            const int c = tid;                     // 256 chunks for B (64x32)
            const int row = c >> 2, cc = (c & 3) * 8;
            char* lb = (char*)&Bs[0][0] + (size_t)(c & ~63) * 16;
            async_cp16(WT + (size_t)(n0 + row) * 1024 + k0 + cc, lb);
        }
        __syncthreads();

        bf16x8 af[4], bfr[2];
        #pragma unroll
        for (int mt = 0; mt < 4; ++mt)
            af[mt] = *(const bf16x8*)&As[wm + mt * 16 + l16][quad * 8];
        #pragma unroll
        for (int nt = 0; nt < 2; ++nt)
            bfr[nt] = *(const bf16x8*)&Bs[wn + nt * 16 + l16][quad * 8];
        #pragma unroll
        for (int mt = 0; mt < 4; ++mt)
            #pragma unroll
            for (int nt = 0; nt < 2; ++nt)
                acc[mt][nt] = __builtin_amdgcn_mfma_f32_16x16x32_bf16(
                    af[mt], bfr[nt], acc[mt][nt], 0, 0, 0);
    }

    #pragma unroll
    for (int nt = 0; nt < 2; ++nt) {
        const int col = n0 + wn + nt * 16 + l16;
        const float bv = bias[col];
        #pragma unroll
        for (int mt = 0; mt < 4; ++mt) {
            #pragma unroll
            for (int r = 0; r < 4; ++r) {
                const int row = m0 + wm + mt * 16 + quad * 4 + r;
                Y[(size_t)row * 1024 + col] = acc[mt][nt][r] + bv;
            }
        }
    }
}

// ---------------- fused MFMA attention (unchanged from round 6/7) -------------
__global__ __launch_bounds__(256) void attn_mfma(
    const u16* __restrict__ Qb, const u16* __restrict__ Kb,
    const u16* __restrict__ VT, const float* __restrict__ csums,
    u16* __restrict__ Cc)
{
    __shared__ __attribute__((aligned(16))) u16 Ks[2][64][64];
    __shared__ __attribute__((aligned(16))) u16 Vs[2][64][64];
    __shared__ __attribute__((aligned(16))) u16 Ps[64][64];

    const int id = blockIdx.x;              // 0..511
    const int xcd = id & 7, j = id >> 3;
    const int h = xcd + 8 * (j >> 5);
    const int s0 = (j & 31) * 64;

    const int tid = threadIdx.x;
    const int lane = tid & 63;
    const int wave = tid >> 6;
    const int quad = lane >> 4;
    const int l16 = lane & 15;
    const int sw = wave * 16;

    const int r_ = tid >> 2;
    const int cq = (tid & 3) * 16;
    const int cq8 = (tid & 3) * 2;

    bf16x8 qf[2][2];
    #pragma unroll
    for (int b = 0; b < 2; ++b)
        #pragma unroll
        for (int ks = 0; ks < 2; ++ks)
            qf[b][ks] = *(const bf16x8*)(Qb + (size_t)(b * S_ + s0 + sw + l16) * 1024
                                          + h * 64 + ks * 32 + quad * 8);

    f32x4 O0[4] = {}, T1[4] = {};

    for (int t0 = 0; t0 < S_; t0 += 64) {
        __syncthreads();
        #pragma unroll
        for (int b = 0; b < 2; ++b) {
            const u16* pk = Kb + (size_t)(b * S_ + t0 + r_) * 1024 + h * 64 + cq;
            *(uint4*)&Ks[b][r_][sw64(r_, cq8)]     = *(const uint4*)pk;
            *(uint4*)&Ks[b][r_][sw64(r_, cq8 + 1)] = *(const uint4*)(pk + 8);
            const u16* pv = VT + ((size_t)(b * H_ + h) * 64 + r_) * 2048 + t0 + cq;
            *(uint4*)&Vs[b][r_][sw64(r_, cq8)]     = *(const uint4*)pv;
            *(uint4*)&Vs[b][r_][sw64(r_, cq8 + 1)] = *(const uint4*)(pv + 8);
        }
        __syncthreads();

        f32x4 dacc[4] = {};
        #pragma unroll
        for (int mt = 0; mt < 4; ++mt) {
            const int kr = mt * 16 + l16;
            #pragma unroll
            for (int ks = 0; ks < 2; ++ks) {
                bf16x8 k0f = *(const bf16x8*)&Ks[0][kr][sw64(kr, ks * 4 + quad)];
                dacc[mt] = __builtin_amdgcn_mfma_f32_16x16x32_bf16(k0f, qf[0][ks], dacc[mt], 0, 0, 0);
                bf16x8 k1f = *(const bf16x8*)&Ks[1][kr][sw64(kr, ks * 4 + quad)];
                dacc[mt] = __builtin_amdgcn_mfma_f32_16x16x32_bf16(k1f, qf[1][ks], dacc[mt], 0, 0, 0);
            }
        }
        const int pr = sw + l16;
        #pragma unroll
        for (int mt = 0; mt < 4; ++mt) {
            float p[4];
            #pragma unroll
            for (int r = 0; r < 4; ++r) {
                float e = __expf(dacc[mt][r] * -0.125f);
                p[r] = __builtin_amdgcn_rcpf(1.0f + e);
            }
            uint2 w;
            w.x = packtr(p[0], p[1]);
            w.y = packtr(p[2], p[3]);
            const int c8 = 2 * mt + (quad >> 1);
            *(uint2*)&Ps[pr][sw64(pr, c8) + (quad & 1) * 4] = w;
        }
        bf16x8 pf0 = *(const bf16x8*)&Ps[pr][sw64(pr, quad)];
        bf16x8 pf1 = *(const bf16x8*)&Ps[pr][sw64(pr, 4 + quad)];
        #pragma unroll
        for (int nt = 0; nt < 4; ++nt) {
            const int vr = nt * 16 + l16;
            bf16x8 v00 = *(const bf16x8*)&Vs[0][vr][sw64(vr, quad)];
            bf16x8 v01 = *(const bf16x8*)&Vs[0][vr][sw64(vr, 4 + quad)];
            O0[nt] = __builtin_amdgcn_mfma_f32_16x16x32_bf16(pf0, v00, O0[nt], 0, 0, 0);
            O0[nt] = __builtin_amdgcn_mfma_f32_16x16x32_bf16(pf1, v01, O0[nt], 0, 0, 0);
            bf16x8 v10 = *(const bf16x8*)&Vs[1][vr][sw64(vr, quad)];
            bf16x8 v11 = *(const bf16x8*)&Vs[1][vr][sw64(vr, 4 + quad)];
            T1[nt] = __builtin_amdgcn_mfma_f32_16x16x32_bf16(pf0, v10, T1[nt], 0, 0, 0);
            T1[nt] = __builtin_amdgcn_mfma_f32_16x16x32_bf16(pf1, v11, T1[nt], 0, 0, 0);
        }
    }

    #pragma unroll
    for (int nt = 0; nt < 4; ++nt) {
        const int dk = nt * 16 + l16;
        const float cs1 = csums[h * 64 + dk];
        #pragma unroll
        for (int r = 0; r < 4; ++r) {
            const int s = s0 + sw + quad * 4 + r;
            Cc[(size_t)(0 * S_ + s) * 1024 + h * 64 + dk] = f2bf(O0[nt][r]);
            Cc[(size_t)(1 * S_ + s) * 1024 + h * 64 + dk] = f2bf(cs1 - T1[nt][r]);
        }
    }
}

extern "C" void kernel_launch(void* const* d_in, const int* in_sizes, int n_in,
                              void* d_out, int out_size, void* d_ws, size_t ws_size,
                              hipStream_t stream) {
    const float* q  = (const float*)d_in[0];
    const float* k  = (const float*)d_in[1];
    const float* v  = (const float*)d_in[2];
    const float* Wq = (const float*)d_in[3];
    const float* bq = (const float*)d_in[4];
    const float* Wk = (const float*)d_in[5];
    const float* bk = (const float*)d_in[6];
    const float* Wv = (const float*)d_in[7];
    const float* bv = (const float*)d_in[8];
    const float* Wo = (const float*)d_in[9];
    const float* bo = (const float*)d_in[10];

    char* ws = (char*)d_ws;
    const size_t MB = 1024 * 1024;
    u16* Cc  = (u16*)(ws);             // 8 MB (shared with Xq — Xq dead by attn)
    u16* Xq  = (u16*)(ws);
    u16* WqT = (u16*)(ws + 8  * MB);
    u16* WkT = (u16*)(ws + 10 * MB);
    u16* WvT = (u16*)(ws + 12 * MB);
    u16* WoT = (u16*)(ws + 14 * MB);
    u16* Qp  = (u16*)(ws + 16 * MB);
    u16* Kp  = (u16*)(ws + 24 * MB);
    u16* Vp  = (u16*)(ws + 32 * MB);
    u16* VTv = (u16*)(ws + 40 * MB);   // shared with Xk (Xk dead by vprep)
    u16* Xk  = (u16*)(ws + 40 * MB);
    u16* Xv  = (u16*)(ws + 48 * MB);   // 8 MB
    float* csums = (float*)d_out;      // scratch; gemm_out overwrites d_out last

    dim3 blk(256);

    PrepArgs pr;
    pr.W[0] = Wq; pr.W[1] = Wk; pr.W[2] = Wv; pr.W[3] = Wo;
    pr.WT[0] = WqT; pr.WT[1] = WkT; pr.WT[2] = WvT; pr.WT[3] = WoT;
    pr.X[0] = q; pr.X[1] = k; pr.X[2] = v;
    pr.XB[0] = Xq; pr.XB[1] = Xk; pr.XB[2] = Xv;
    pr.csums = csums;
    prep<<<dim3(1024 + 6144), blk, 0, stream>>>(pr);

    ProjArgs pa;
    pa.X[0] = Xq; pa.X[1] = Xk; pa.X[2] = Xv;
    pa.W[0] = WqT; pa.W[1] = WkT; pa.W[2] = WvT;
    pa.bias[0] = bq; pa.bias[1] = bk; pa.bias[2] = bv;
    pa.Y[0] = Qp; pa.Y[1] = Kp; pa.Y[2] = Vp;
    proj3<<<dim3(32, 8, 3), blk, 0, stream>>>(pa);

    vprep<<<dim3(32, 32), blk, 0, stream>>>(Vp, VTv, csums);
    attn_mfma<<<dim3(512), blk, 0, stream>>>(Qp, Kp, VTv, csums, Cc);
    gemm_out<<<dim3(32, 16), blk, 0, stream>>>(Cc, WoT, bo, (float*)d_out);
}